// Round 1
// baseline (110.888 us; speedup 1.0000x reference)
//
#include <hip/hip_runtime.h>
#include <math.h>

#define POOL 7
#define FH 50
#define FW 50
#define FC 1024

// One block per (roi, bin_i, bin_j). 256 threads * float4 = 1024 channels.
__global__ __launch_bounds__(256) void roipool_kernel(
    const float* __restrict__ fm,     // [FH, FW, FC]
    const float* __restrict__ rois,   // [N, 4] (y1, x1, y2, x2) normalized
    float* __restrict__ out)          // [N, 7, 7, FC]
{
    const int bid = blockIdx.x;           // n*49 + i*7 + j
    const int n  = bid / 49;
    const int ij = bid - n * 49;
    const int i  = ij / 7;
    const int j  = ij - i * 7;

    // ROI corners: truncating float->int cast, matching jnp astype(int32)
    const float4 roi = reinterpret_cast<const float4*>(rois)[n];
    const int h0 = (int)((float)FH * roi.x);
    const int w0 = (int)((float)FW * roi.y);
    const int h1 = (int)((float)FH * roi.z);
    const int w1 = (int)((float)FW * roi.w);
    const int rh = h1 - h0;
    const int rw = w1 - w0;
    const int hstep = rh / POOL;   // rh >= 0, truncation == floor
    const int wstep = rw / POOL;

    // bin bounds (region-relative) + empty-bin adjustment
    int sh = i * hstep;
    int eh = (i < POOL - 1) ? (i + 1) * hstep : rh;
    if (sh == eh) { if (eh < rh) eh += 1; else sh -= 1; }
    int sw = j * wstep;
    int ew = (j < POOL - 1) ? (j + 1) * wstep : rw;
    if (sw == ew) { if (ew < rw) ew += 1; else sw -= 1; }

    // global row/col range, clamped to the feature map (mask semantics)
    const int r0 = max(0, h0 + sh);
    const int r1 = min(FH, h0 + eh);
    const int c0 = max(0, w0 + sw);
    const int c1 = min(FW, w0 + ew);

    const int t = threadIdx.x;  // 0..255 -> 4 channels each (float4)

    float4 acc;
    acc.x = -INFINITY; acc.y = -INFINITY; acc.z = -INFINITY; acc.w = -INFINITY;

    for (int r = r0; r < r1; ++r) {
        const float4* row = reinterpret_cast<const float4*>(fm + ((size_t)(r * FW)) * FC);
        for (int c = c0; c < c1; ++c) {
            float4 v = row[c * (FC / 4) + t];
            acc.x = fmaxf(acc.x, v.x);
            acc.y = fmaxf(acc.y, v.y);
            acc.z = fmaxf(acc.z, v.z);
            acc.w = fmaxf(acc.w, v.w);
        }
    }

    reinterpret_cast<float4*>(out + (size_t)bid * FC)[t] = acc;
}

extern "C" void kernel_launch(void* const* d_in, const int* in_sizes, int n_in,
                              void* d_out, int out_size, void* d_ws, size_t ws_size,
                              hipStream_t stream) {
    const float* features = (const float*)d_in[0];  // [1,50,50,1024]
    const float* rois     = (const float*)d_in[1];  // [N,4]
    float* out            = (float*)d_out;          // [N,7,7,1024]
    const int N = in_sizes[1] / 4;

    dim3 grid(N * POOL * POOL);
    dim3 block(256);
    roipool_kernel<<<grid, block, 0, stream>>>(features, rois, out);
}

// Round 2
// 102.546 us; speedup vs baseline: 1.0813x; 1.0813x over previous
//
#include <hip/hip_runtime.h>
#include <math.h>

#define POOL 7
#define FH 50
#define FW 50
#define FC 1024
#define FC4 (FC / 4)   // 256 float4 groups per spatial cell

typedef float vf4 __attribute__((ext_vector_type(4)));

static __device__ __forceinline__ vf4 vmax4(vf4 a, vf4 b) {
    vf4 r;
    r.x = fmaxf(a.x, b.x);
    r.y = fmaxf(a.y, b.y);
    r.z = fmaxf(a.z, b.z);
    r.w = fmaxf(a.w, b.w);
    return r;
}

// One wave (64 threads) per (roi, bin_i, bin_j). Each thread owns 16 channels
// (4 x float4), giving 4 independent loads per cell; columns unrolled x2 ->
// up to 8 loads in flight before the fmax chain consumes them.
__global__ __launch_bounds__(64) void roipool_kernel(
    const float* __restrict__ fm,     // [FH, FW, FC]
    const float* __restrict__ rois,   // [N, 4] (y1, x1, y2, x2) normalized
    float* __restrict__ out)          // [N, 7, 7, FC]
{
    const int bid = blockIdx.x;           // n*49 + i*7 + j
    const int n  = bid / 49;
    const int ij = bid - n * 49;
    const int i  = ij / 7;
    const int j  = ij - i * 7;

    // ROI corners: truncating float->int cast, matching jnp astype(int32)
    const float4 roi = reinterpret_cast<const float4*>(rois)[n];
    const int h0 = (int)((float)FH * roi.x);
    const int w0 = (int)((float)FW * roi.y);
    const int h1 = (int)((float)FH * roi.z);
    const int w1 = (int)((float)FW * roi.w);
    const int rh = h1 - h0;
    const int rw = w1 - w0;
    const int hstep = rh / POOL;
    const int wstep = rw / POOL;

    // bin bounds (region-relative) + empty-bin adjustment
    int sh = i * hstep;
    int eh = (i < POOL - 1) ? (i + 1) * hstep : rh;
    if (sh == eh) { if (eh < rh) eh += 1; else sh -= 1; }
    int sw = j * wstep;
    int ew = (j < POOL - 1) ? (j + 1) * wstep : rw;
    if (sw == ew) { if (ew < rw) ew += 1; else sw -= 1; }

    // global row/col range, clamped to the feature map (mask semantics)
    const int r0 = max(0, h0 + sh);
    const int r1 = min(FH, h0 + eh);
    const int c0 = max(0, w0 + sw);
    const int c1 = min(FW, w0 + ew);

    const int t = threadIdx.x;  // 0..63

    vf4 acc0 = {-INFINITY, -INFINITY, -INFINITY, -INFINITY};
    vf4 acc1 = acc0, acc2 = acc0, acc3 = acc0;

    const vf4* fm4 = reinterpret_cast<const vf4*>(fm);

    for (int r = r0; r < r1; ++r) {
        const vf4* rowp = fm4 + (size_t)(r * FW) * FC4;
        int c = c0;
        for (; c + 1 < c1; c += 2) {
            const vf4* p0 = rowp + (size_t)c * FC4;
            const vf4* p1 = rowp + (size_t)(c + 1) * FC4;
            vf4 a0 = p0[t];
            vf4 a1 = p0[t + 64];
            vf4 a2 = p0[t + 128];
            vf4 a3 = p0[t + 192];
            vf4 b0 = p1[t];
            vf4 b1 = p1[t + 64];
            vf4 b2 = p1[t + 128];
            vf4 b3 = p1[t + 192];
            acc0 = vmax4(acc0, vmax4(a0, b0));
            acc1 = vmax4(acc1, vmax4(a1, b1));
            acc2 = vmax4(acc2, vmax4(a2, b2));
            acc3 = vmax4(acc3, vmax4(a3, b3));
        }
        if (c < c1) {
            const vf4* p0 = rowp + (size_t)c * FC4;
            vf4 a0 = p0[t];
            vf4 a1 = p0[t + 64];
            vf4 a2 = p0[t + 128];
            vf4 a3 = p0[t + 192];
            acc0 = vmax4(acc0, a0);
            acc1 = vmax4(acc1, a1);
            acc2 = vmax4(acc2, a2);
            acc3 = vmax4(acc3, a3);
        }
    }

    vf4* o = reinterpret_cast<vf4*>(out) + (size_t)bid * FC4;
    __builtin_nontemporal_store(acc0, o + t);
    __builtin_nontemporal_store(acc1, o + t + 64);
    __builtin_nontemporal_store(acc2, o + t + 128);
    __builtin_nontemporal_store(acc3, o + t + 192);
}

extern "C" void kernel_launch(void* const* d_in, const int* in_sizes, int n_in,
                              void* d_out, int out_size, void* d_ws, size_t ws_size,
                              hipStream_t stream) {
    const float* features = (const float*)d_in[0];  // [1,50,50,1024]
    const float* rois     = (const float*)d_in[1];  // [N,4]
    float* out            = (float*)d_out;          // [N,7,7,1024]
    const int N = in_sizes[1] / 4;

    dim3 grid(N * POOL * POOL);
    dim3 block(64);
    roipool_kernel<<<grid, block, 0, stream>>>(features, rois, out);
}